// Round 1
// baseline (597.060 us; speedup 1.0000x reference)
//
#include <hip/hip_runtime.h>
#include <cstdint>
#include <cstddef>

#define NBATCH 128
#define NCH    256
#define NHW    1024
#define NTIME  64
#define NCLS   128

typedef _Float16 half2_t __attribute__((ext_vector_type(2)));

#if defined(__has_builtin)
#  if __has_builtin(__builtin_amdgcn_fdot2)
#    define HAS_FDOT2 1
#  endif
#endif
#ifndef HAS_FDOT2
#  define HAS_FDOT2 0
#endif

__device__ __forceinline__ float dot2acc(half2_t a, half2_t b, float c){
#if HAS_FDOT2
  return __builtin_amdgcn_fdot2(a, b, c, false);
#else
  return c + (float)a.x*(float)b.x + (float)a.y*(float)b.y;
#endif
}

__device__ __forceinline__ float sig_(float x){
  x = fminf(30.f, fmaxf(-30.f, x));
  return 1.f/(1.f+__expf(-x));
}
__device__ __forceinline__ float tanh_(float x){
  x = fminf(15.f, fmaxf(-15.f, x));
  float e = __expf(2.f*x);
  return (e-1.f)/(e+1.f);
}

// ---------------- K0: row sums of A -> S[b*64+t] ----------------
__global__ __launch_bounds__(256) void k_rowsum(const float* __restrict__ A, float* __restrict__ S){
  int row = blockIdx.x;                       // b*64+t
  const float4* a4 = (const float4*)(A + (size_t)row*NHW);
  float4 v = a4[threadIdx.x];
  float s = v.x+v.y+v.z+v.w;
  #pragma unroll
  for (int off=32; off>0; off>>=1) s += __shfl_down(s, off, 64);
  __shared__ float wsum[4];
  int lane = threadIdx.x & 63, w = threadIdx.x >> 6;
  if (lane==0) wsum[w] = s;
  __syncthreads();
  if (threadIdx.x==0) S[row] = wsum[0]+wsum[1]+wsum[2]+wsum[3];
}

// ---------------- K1: attention pooling  C[t][b][c] = sum_hw feat[b][c][hw]*A[b][t][hw]/S ---
__global__ __launch_bounds__(256) void k_pool(const float* __restrict__ feat, const float* __restrict__ A,
                                              const float* __restrict__ S, float* __restrict__ C){
  __shared__ float As[64*65];
  __shared__ float Fs[64*65];
  __shared__ float sinv[64];
  int b = blockIdx.x, c0 = blockIdx.y*64, tid = threadIdx.x;
  if (tid < 64) sinv[tid] = 1.f / S[b*64 + tid];
  float acc[4][4] = {};
  int rq = tid>>4, cq = tid&15;
  for (int k0=0;k0<NHW;k0+=64){
    __syncthreads();
    #pragma unroll
    for (int j=0;j<4;j++){
      int f4 = j*256+tid, r = f4>>4, cc = (f4&15)*4;
      float4 va = *(const float4*)(A + ((size_t)(b*64+r))*NHW + k0 + cc);
      As[r*65+cc+0]=va.x; As[r*65+cc+1]=va.y; As[r*65+cc+2]=va.z; As[r*65+cc+3]=va.w;
      float4 vf = *(const float4*)(feat + ((size_t)(b*256+c0+r))*NHW + k0 + cc);
      Fs[r*65+cc+0]=vf.x; Fs[r*65+cc+1]=vf.y; Fs[r*65+cc+2]=vf.z; Fs[r*65+cc+3]=vf.w;
    }
    __syncthreads();
    #pragma unroll 8
    for (int k=0;k<64;k++){
      float xa[4], wb[4];
      #pragma unroll
      for (int i=0;i<4;i++) xa[i] = As[(rq*4+i)*65+k];
      #pragma unroll
      for (int j=0;j<4;j++) wb[j] = Fs[(cq*4+j)*65+k];
      #pragma unroll
      for (int i=0;i<4;i++)
        #pragma unroll
        for (int j=0;j<4;j++) acc[i][j] += xa[i]*wb[j];
    }
  }
  #pragma unroll
  for (int i=0;i<4;i++){
    int t = rq*4+i;
    float is = sinv[t];
    float4 o; o.x=acc[i][0]*is; o.y=acc[i][1]*is; o.z=acc[i][2]*is; o.w=acc[i][3]*is;
    *(float4*)(C + ((size_t)t*NBATCH + b)*NCH + c0 + cq*4) = o;
  }
}

// ---------------- generic GEMM: out[M][N] = X[M][K] @ W[N][K]^T + ba + bb ----------------
__global__ __launch_bounds__(256) void k_gemm_bias(const float* __restrict__ X, const float* __restrict__ W,
    const float* __restrict__ ba, const float* __restrict__ bb, float* __restrict__ out, int N, int K){
  __shared__ float Xs[64*65];
  __shared__ float Ws[64*65];
  int m0 = blockIdx.y*64, n0 = blockIdx.x*64, tid = threadIdx.x;
  float acc[4][4] = {};
  int rq = tid>>4, cq = tid&15;
  for (int k0=0;k0<K;k0+=64){
    __syncthreads();
    #pragma unroll
    for (int j=0;j<4;j++){
      int f4 = j*256+tid, r = f4>>4, cc = (f4&15)*4;
      float4 vx = *(const float4*)(X + (size_t)(m0+r)*K + k0 + cc);
      Xs[r*65+cc+0]=vx.x; Xs[r*65+cc+1]=vx.y; Xs[r*65+cc+2]=vx.z; Xs[r*65+cc+3]=vx.w;
      float4 vw = *(const float4*)(W + (size_t)(n0+r)*K + k0 + cc);
      Ws[r*65+cc+0]=vw.x; Ws[r*65+cc+1]=vw.y; Ws[r*65+cc+2]=vw.z; Ws[r*65+cc+3]=vw.w;
    }
    __syncthreads();
    #pragma unroll 8
    for (int k=0;k<64;k++){
      float xa[4], wb[4];
      #pragma unroll
      for (int i=0;i<4;i++) xa[i] = Xs[(rq*4+i)*65+k];
      #pragma unroll
      for (int j=0;j<4;j++) wb[j] = Ws[(cq*4+j)*65+k];
      #pragma unroll
      for (int i=0;i<4;i++)
        #pragma unroll
        for (int j=0;j<4;j++) acc[i][j] += xa[i]*wb[j];
    }
  }
  float bs[4];
  #pragma unroll
  for (int j=0;j<4;j++){ int n = n0+cq*4+j; bs[j] = ba[n] + (bb ? bb[n] : 0.f); }
  #pragma unroll
  for (int i=0;i<4;i++){
    float4 o; o.x=acc[i][0]+bs[0]; o.y=acc[i][1]+bs[1]; o.z=acc[i][2]+bs[2]; o.w=acc[i][3]+bs[3];
    *(float4*)(out + (size_t)(m0+rq*4+i)*N + n0 + cq*4) = o;
  }
}

// ---------------- K7: packed normalized attention output ----------------
__global__ __launch_bounds__(256) void k_attns(const float* __restrict__ A, const float* __restrict__ S,
    const int* __restrict__ pack_b, const int* __restrict__ pack_t, float* __restrict__ outA){
  int i = blockIdx.x;
  int b = pack_b[i], t = pack_t[i];
  float is = 1.f / S[b*64 + t];
  float4 v = ((const float4*)(A + ((size_t)(b*64+t))*NHW))[threadIdx.x];
  v.x*=is; v.y*=is; v.z*=is; v.w*=is;
  ((float4*)(outA + (size_t)i*NHW))[threadIdx.x] = v;
}

// ---------------- K3: BiLSTM scan. 256 blocks = 128 samples x 2 dirs, 512 thr = 512 gates ---
__global__ __launch_bounds__(512) void k_lstm(const float* __restrict__ Gf, const float* __restrict__ Gb,
    const float* __restrict__ Whh_f, const float* __restrict__ Whh_b, float* __restrict__ Cl){
  int b = blockIdx.x & 127, dir = blockIdx.x >> 7;
  int g = threadIdx.x;
  const float* Whh = dir ? Whh_b : Whh_f;
  const float* G   = dir ? Gb    : Gf;
  float4 w4[32];
  const float4* wr = (const float4*)(Whh + (size_t)g*128);
  #pragma unroll
  for (int j=0;j<32;j++) w4[j] = wr[j];
  __shared__ float4 h4[32];
  __shared__ float gates[512];
  float* hL = (float*)h4;
  if (g < 32) h4[g] = make_float4(0.f,0.f,0.f,0.f);
  float c = 0.f;
  __syncthreads();
  for (int t=0;t<NTIME;t++){
    int tt = dir ? (NTIME-1-t) : t;
    float a0 = G[((size_t)tt*NBATCH + b)*512 + g], a1=0.f, a2=0.f, a3=0.f;
    #pragma unroll
    for (int j=0;j<32;j+=4){
      float4 h0=h4[j], h1=h4[j+1], h2=h4[j+2], h3=h4[j+3];
      a0 += w4[j  ].x*h0.x + w4[j  ].y*h0.y + w4[j  ].z*h0.z + w4[j  ].w*h0.w;
      a1 += w4[j+1].x*h1.x + w4[j+1].y*h1.y + w4[j+1].z*h1.z + w4[j+1].w*h1.w;
      a2 += w4[j+2].x*h2.x + w4[j+2].y*h2.y + w4[j+2].z*h2.z + w4[j+2].w*h2.w;
      a3 += w4[j+3].x*h3.x + w4[j+3].y*h3.y + w4[j+3].z*h3.z + w4[j+3].w*h3.w;
    }
    gates[g] = a0+a1+a2+a3;
    __syncthreads();
    if (g < 128){
      float gi=gates[g], gf=gates[128+g], gg=gates[256+g], go=gates[384+g];
      c = sig_(gf)*c + sig_(gi)*tanh_(gg);
      float h = sig_(go)*tanh_(c);
      hL[g] = h;
      Cl[((size_t)tt*NBATCH + b)*NCH + dir*128 + g] = h;
    }
    __syncthreads();
  }
}

// ---------------- K4a: xs = [Cl, prev_emb] ----------------
__global__ __launch_bounds__(256) void k_xs(const float* __restrict__ Cl, const float* __restrict__ emb,
    const int* __restrict__ text, float* __restrict__ xs){
  int idx = blockIdx.x*256 + threadIdx.x;     // float4 index, 1,048,576 total
  int row = idx>>7, c4 = idx&127;             // row = t*128+b, 128 float4 per row
  int t = row>>7, b = row&127;
  float4 v;
  if (c4 < 64) v = ((const float4*)Cl)[(size_t)row*64 + c4];
  else {
    int cls = (t==0) ? 0 : text[b*64 + (t-1)];
    v = ((const float4*)emb)[(size_t)cls*64 + (c4-64)];
  }
  ((float4*)xs)[(size_t)row*128 + c4] = v;
}

// ---------------- K5: GRU scan. 128 blocks = samples, 768 thr = gates, f16 weights in regs ---
__global__ __launch_bounds__(768) void k_gru(const float* __restrict__ gx, const float* __restrict__ Whh_g,
    const float* __restrict__ bhh_g, float* __restrict__ hs){
  int b = blockIdx.x, g = threadIdx.x;
  half2_t wp[128];
  const float4* wr = (const float4*)(Whh_g + (size_t)g*256);
  #pragma unroll
  for (int j=0;j<64;j++){
    float4 v = wr[j];
    half2_t p0; p0.x=(_Float16)v.x; p0.y=(_Float16)v.y;
    half2_t p1; p1.x=(_Float16)v.z; p1.y=(_Float16)v.w;
    wp[2*j] = p0; wp[2*j+1] = p1;
  }
  float bh = bhh_g[g];
  __shared__ float h32[256];
  __shared__ half2_t h16[128];
  __shared__ float ghs[768];
  if (g < 256) h32[g] = 0.f;
  if (g < 128){ half2_t z; z.x=(_Float16)0.f; z.y=(_Float16)0.f; h16[g]=z; }
  __syncthreads();
  for (int t=0;t<NTIME;t++){
    float a0=bh, a1=0.f, a2=0.f, a3=0.f;
    #pragma unroll
    for (int j=0;j<128;j+=4){
      a0 = dot2acc(wp[j  ], h16[j  ], a0);
      a1 = dot2acc(wp[j+1], h16[j+1], a1);
      a2 = dot2acc(wp[j+2], h16[j+2], a2);
      a3 = dot2acc(wp[j+3], h16[j+3], a3);
    }
    ghs[g] = a0+a1+a2+a3;
    __syncthreads();
    if (g < 256){
      const float* gxp = gx + ((size_t)t*NBATCH + b)*768;
      float r = sig_(gxp[g]       + ghs[g]);
      float z = sig_(gxp[256+g]   + ghs[256+g]);
      float n = tanh_(gxp[512+g]  + r*ghs[512+g]);
      float h = (1.f-z)*n + z*h32[g];
      h32[g] = h;
      hs[((size_t)t*NBATCH + b)*NCH + g] = h;
    }
    __syncthreads();
    if (g < 128){ half2_t p; p.x=(_Float16)h32[2*g]; p.y=(_Float16)h32[2*g+1]; h16[g]=p; }
    __syncthreads();
  }
}

// ---------------- K6: logits for packed rows (gather + GEMM + bias) ----------------
__global__ __launch_bounds__(256) void k_logits(const float* __restrict__ hs, const int* __restrict__ pack_t,
    const int* __restrict__ pack_b, const float* __restrict__ W, const float* __restrict__ bias,
    float* __restrict__ out, int L){
  __shared__ float Xs[64*65];
  __shared__ float Ws[64*65];
  __shared__ int rt[64], rb[64];
  int m0 = blockIdx.y*64, n0 = blockIdx.x*64, tid = threadIdx.x;
  if (tid < 64){
    int m = m0 + tid;
    rt[tid] = (m<L) ? pack_t[m] : 0;
    rb[tid] = (m<L) ? pack_b[m] : 0;
  }
  float acc[4][4] = {};
  int rq = tid>>4, cq = tid&15;
  __syncthreads();
  for (int k0=0;k0<256;k0+=64){
    __syncthreads();
    #pragma unroll
    for (int j=0;j<4;j++){
      int f4 = j*256+tid, r = f4>>4, cc = (f4&15)*4;
      float4 vx = *(const float4*)(hs + ((size_t)rt[r]*NBATCH + rb[r])*NCH + k0 + cc);
      Xs[r*65+cc+0]=vx.x; Xs[r*65+cc+1]=vx.y; Xs[r*65+cc+2]=vx.z; Xs[r*65+cc+3]=vx.w;
      float4 vw = *(const float4*)(W + (size_t)(n0+r)*256 + k0 + cc);
      Ws[r*65+cc+0]=vw.x; Ws[r*65+cc+1]=vw.y; Ws[r*65+cc+2]=vw.z; Ws[r*65+cc+3]=vw.w;
    }
    __syncthreads();
    #pragma unroll 8
    for (int k=0;k<64;k++){
      float xa[4], wb[4];
      #pragma unroll
      for (int i=0;i<4;i++) xa[i] = Xs[(rq*4+i)*65+k];
      #pragma unroll
      for (int j=0;j<4;j++) wb[j] = Ws[(cq*4+j)*65+k];
      #pragma unroll
      for (int i=0;i<4;i++)
        #pragma unroll
        for (int j=0;j<4;j++) acc[i][j] += xa[i]*wb[j];
    }
  }
  float bs[4];
  #pragma unroll
  for (int j=0;j<4;j++) bs[j] = bias[n0+cq*4+j];
  #pragma unroll
  for (int i=0;i<4;i++){
    int m = m0 + rq*4 + i;
    if (m < L){
      float4 o; o.x=acc[i][0]+bs[0]; o.y=acc[i][1]+bs[1]; o.z=acc[i][2]+bs[2]; o.w=acc[i][3]+bs[3];
      *(float4*)(out + (size_t)m*NCLS + n0 + cq*4) = o;
    }
  }
}

extern "C" void kernel_launch(void* const* d_in, const int* in_sizes, int n_in,
                              void* d_out, int out_size, void* d_ws, size_t ws_size,
                              hipStream_t stream) {
  const float* feature = (const float*)d_in[0];
  const float* A       = (const float*)d_in[1];
  const int*   text    = (const int*)d_in[2];
  const int*   pack_b  = (const int*)d_in[4];
  const int*   pack_t  = (const int*)d_in[5];
  const float* emb     = (const float*)d_in[6];
  const float* Wih_f   = (const float*)d_in[7];
  const float* Whh_f   = (const float*)d_in[8];
  const float* bih_f   = (const float*)d_in[9];
  const float* bhh_f   = (const float*)d_in[10];
  const float* Wih_b   = (const float*)d_in[11];
  const float* Whh_b   = (const float*)d_in[12];
  const float* bih_b   = (const float*)d_in[13];
  const float* bhh_b   = (const float*)d_in[14];
  const float* Wih_g   = (const float*)d_in[15];
  const float* Whh_g   = (const float*)d_in[16];
  const float* bih_g   = (const float*)d_in[17];
  const float* bhh_g   = (const float*)d_in[18];
  const float* Wgen    = (const float*)d_in[19];
  const float* bgen    = (const float*)d_in[20];
  int L = in_sizes[4];

  char* ws = (char*)d_ws;
  const size_t MB = 1u<<20;
  float* S   = (float*)(ws + 0);
  float* C   = (float*)(ws + 1*MB);    // 8 MB  [t][b][256]
  float* Cl  = (float*)(ws + 9*MB);    // 8 MB  [t][b][256]
  float* hs  = (float*)(ws + 17*MB);   // 8 MB  [t][b][256]
  float* Gf  = (float*)(ws + 25*MB);   // 16 MB [t][b][512]  (dead after k_lstm)
  float* Gb  = (float*)(ws + 41*MB);   // 16 MB [t][b][512]  (dead after k_lstm)
  float* xs  = (float*)(ws + 25*MB);   // 16 MB, aliases Gf (written after k_lstm)
  float* gx  = (float*)(ws + 41*MB);   // 24 MB, aliases Gb (written after k_lstm)

  float* out_res   = (float*)d_out;
  float* out_attns = out_res + (size_t)L*NCLS;

  k_rowsum<<<8192, 256, 0, stream>>>(A, S);
  k_pool<<<dim3(128,4), 256, 0, stream>>>(feature, A, S, C);
  k_attns<<<L, 256, 0, stream>>>(A, S, pack_b, pack_t, out_attns);
  k_gemm_bias<<<dim3(8,128), 256, 0, stream>>>(C, Wih_f, bih_f, bhh_f, Gf, 512, 256);
  k_gemm_bias<<<dim3(8,128), 256, 0, stream>>>(C, Wih_b, bih_b, bhh_b, Gb, 512, 256);
  k_lstm<<<256, 512, 0, stream>>>(Gf, Gb, Whh_f, Whh_b, Cl);
  k_xs<<<4096, 256, 0, stream>>>(Cl, emb, text, xs);
  k_gemm_bias<<<dim3(12,128), 256, 0, stream>>>(xs, Wih_g, bih_g, nullptr, gx, 768, 512);
  k_gru<<<128, 768, 0, stream>>>(gx, Whh_g, bhh_g, hs);
  k_logits<<<dim3(2,(L+63)/64), 256, 0, stream>>>(hs, pack_t, pack_b, Wgen, bgen, out_res, L);
}